// Round 1
// baseline (1746.257 us; speedup 1.0000x reference)
//
#include <hip/hip_runtime.h>
#include <math.h>

#define NN 100000
#define NE 3200000

// ---------------- K1: h1 = relu(x@W1+b1); h2 = relu(h1@W2+b2) ----------------
// grid 8 x 64. Each block redundantly computes full h1 (W1 hits L2 after blk0),
// then its 64-column slice of h2.
__global__ __launch_bounds__(64) void mlp12_kernel(
        const float* __restrict__ x,
        const float* __restrict__ W1, const float* __restrict__ b1,
        const float* __restrict__ W2, const float* __restrict__ b2,
        float* __restrict__ h2g) {
    __shared__ float xs[128];
    __shared__ float h1s[256];
    int t = threadIdx.x;
    xs[t] = x[t];
    xs[t + 64] = x[t + 64];
    __syncthreads();
    for (int cc = 0; cc < 4; ++cc) {
        int c = t + cc * 64;
        float acc = b1[c];
        for (int k = 0; k < 128; ++k) acc = fmaf(xs[k], W1[k * 256 + c], acc);
        h1s[c] = fmaxf(acc, 0.0f);
    }
    __syncthreads();
    int c2 = blockIdx.x * 64 + t;
    float acc = b2[c2];
    for (int k = 0; k < 256; ++k) acc = fmaf(h1s[k], W2[k * 512 + c2], acc);
    h2g[c2] = fmaxf(acc, 0.0f);
}

// ---------------- K2: h3 = relu(h2@W3+b3); m1 = h3_node(4) @ Wg1(4x2) --------
// block 256 = 4 k-slices x 64 nodes. Lane = node_sub -> float4 loads of W3 row
// are 16B/lane contiguous (1KB/wave, perfectly coalesced).
__global__ __launch_bounds__(256) void big_layer_kernel(
        const float* __restrict__ h2, const float* __restrict__ W3,
        const float* __restrict__ b3, const float* __restrict__ Wg1,
        float* __restrict__ m1) {
    __shared__ float h2s[512];
    __shared__ float ps[4][64][4];
    int t = threadIdx.x;
    h2s[t] = h2[t];
    h2s[t + 256] = h2[t + 256];
    __syncthreads();
    int ks = t >> 6;        // k-slice 0..3
    int ns = t & 63;        // node within block
    int node = blockIdx.x * 64 + ns;
    float a0 = 0.f, a1 = 0.f, a2 = 0.f, a3 = 0.f;
    if (node < NN) {
        int k0 = ks * 128;
        const float4* p =
            reinterpret_cast<const float4*>(W3 + (size_t)k0 * 400000 + 4 * (size_t)node);
        for (int it = 0; it < 128; ++it) {
            float4 w = p[(size_t)it * 100000];   // row stride 400000 floats
            float hv = h2s[k0 + it];             // LDS broadcast (uniform per group)
            a0 = fmaf(hv, w.x, a0);
            a1 = fmaf(hv, w.y, a1);
            a2 = fmaf(hv, w.z, a2);
            a3 = fmaf(hv, w.w, a3);
        }
    }
    ps[ks][ns][0] = a0; ps[ks][ns][1] = a1; ps[ks][ns][2] = a2; ps[ks][ns][3] = a3;
    __syncthreads();
    if (ks == 0 && node < NN) {
        float t0 = ps[0][ns][0] + ps[1][ns][0] + ps[2][ns][0] + ps[3][ns][0];
        float t1 = ps[0][ns][1] + ps[1][ns][1] + ps[2][ns][1] + ps[3][ns][1];
        float t2 = ps[0][ns][2] + ps[1][ns][2] + ps[2][ns][2] + ps[3][ns][2];
        float t3 = ps[0][ns][3] + ps[1][ns][3] + ps[2][ns][3] + ps[3][ns][3];
        const float4 bb = *reinterpret_cast<const float4*>(b3 + 4 * (size_t)node);
        t0 = fmaxf(t0 + bb.x, 0.0f);
        t1 = fmaxf(t1 + bb.y, 0.0f);
        t2 = fmaxf(t2 + bb.z, 0.0f);
        t3 = fmaxf(t3 + bb.w, 0.0f);
        // m1 = h3_node @ Wg1, Wg1 row-major (4,2)
        float m0 = t0 * Wg1[0] + t1 * Wg1[2] + t2 * Wg1[4] + t3 * Wg1[6];
        float mv = t0 * Wg1[1] + t1 * Wg1[3] + t2 * Wg1[5] + t3 * Wg1[7];
        m1[2 * node]     = m0;
        m1[2 * node + 1] = mv;
    }
}

// ---------------- K3: degree count (dst) -------------------------------------
__global__ __launch_bounds__(256) void deg_kernel(const int* __restrict__ dst,
                                                  float* __restrict__ deg) {
    int e = blockIdx.x * 256 + threadIdx.x;
    if (e < NE) atomicAdd(&deg[dst[e]], 1.0f);
}

// ---------------- K4: dinv = rsqrt(deg+1); agg1 = m1 * (1/deg) ---------------
__global__ __launch_bounds__(256) void node1_kernel(const float* __restrict__ deg,
                                                    const float* __restrict__ m1,
                                                    float* __restrict__ dinv,
                                                    float* __restrict__ agg1) {
    int i = blockIdx.x * 256 + threadIdx.x;
    if (i < NN) {
        float d = deg[i] + 1.0f;
        dinv[i] = rsqrtf(d);
        float inv = 1.0f / d;
        agg1[2 * i]     = m1[2 * i] * inv;
        agg1[2 * i + 1] = m1[2 * i + 1] * inv;
    }
}

// ---------------- K5: GCN1 edge scatter --------------------------------------
__global__ __launch_bounds__(256) void edge1_kernel(const int* __restrict__ src,
                                                    const int* __restrict__ dst,
                                                    const float* __restrict__ dinv,
                                                    const float* __restrict__ m1,
                                                    float* __restrict__ agg1) {
    int e = blockIdx.x * 256 + threadIdx.x;
    if (e < NE) {
        int s = src[e], d = dst[e];
        float n = dinv[s] * dinv[d];
        atomicAdd(&agg1[2 * d],     m1[2 * s] * n);
        atomicAdd(&agg1[2 * d + 1], m1[2 * s + 1] * n);
    }
}

// ------- K6: g1 = relu(agg1+bg1); m2 = g1@Wg2; agg2 = m2*(1/deg) -------------
__global__ __launch_bounds__(256) void node2_kernel(const float* __restrict__ agg1,
                                                    const float* __restrict__ bg1,
                                                    const float* __restrict__ Wg2,
                                                    const float* __restrict__ deg,
                                                    float* __restrict__ m2,
                                                    float* __restrict__ agg2) {
    int i = blockIdx.x * 256 + threadIdx.x;
    if (i < NN) {
        float g0 = fmaxf(agg1[2 * i] + bg1[0], 0.0f);
        float g1 = fmaxf(agg1[2 * i + 1] + bg1[1], 0.0f);
        float mv = g0 * Wg2[0] + g1 * Wg2[1];
        m2[i] = mv;
        float d = deg[i] + 1.0f;
        agg2[i] = mv / d;
    }
}

// ---------------- K7: GCN2 edge scatter --------------------------------------
__global__ __launch_bounds__(256) void edge2_kernel(const int* __restrict__ src,
                                                    const int* __restrict__ dst,
                                                    const float* __restrict__ dinv,
                                                    const float* __restrict__ m2,
                                                    float* __restrict__ agg2) {
    int e = blockIdx.x * 256 + threadIdx.x;
    if (e < NE) {
        int s = src[e], d = dst[e];
        atomicAdd(&agg2[d], m2[s] * dinv[s] * dinv[d]);
    }
}

// ---------------- K8: out = sigmoid(agg2 + bg2) ------------------------------
__global__ __launch_bounds__(256) void sigmoid_kernel(const float* __restrict__ agg2,
                                                      const float* __restrict__ bg2,
                                                      float* __restrict__ out) {
    int i = blockIdx.x * 256 + threadIdx.x;
    if (i < NN) {
        float v = agg2[i] + bg2[0];
        out[i] = 1.0f / (1.0f + __expf(-v));
    }
}

extern "C" void kernel_launch(void* const* d_in, const int* in_sizes, int n_in,
                              void* d_out, int out_size, void* d_ws, size_t ws_size,
                              hipStream_t stream) {
    const float* x   = (const float*)d_in[0];
    const int*   ei  = (const int*)d_in[1];     // (2, E) int32
    const float* W1  = (const float*)d_in[2];
    const float* b1  = (const float*)d_in[3];
    const float* W2  = (const float*)d_in[4];
    const float* b2  = (const float*)d_in[5];
    const float* W3  = (const float*)d_in[6];
    const float* b3  = (const float*)d_in[7];
    const float* Wg1 = (const float*)d_in[8];
    const float* bg1 = (const float*)d_in[9];
    const float* Wg2 = (const float*)d_in[10];
    const float* bg2 = (const float*)d_in[11];
    float* out = (float*)d_out;

    const int* src = ei;
    const int* dst = ei + NE;

    // workspace layout (floats)
    float* ws   = (float*)d_ws;
    float* h2   = ws;                   // 512
    float* m1   = h2 + 512;             // 2N
    float* deg  = m1 + 2 * NN;          // N
    float* dinv = deg + NN;             // N
    float* agg1 = dinv + NN;            // 2N
    float* m2   = agg1 + 2 * NN;        // N
    float* agg2 = m2 + NN;              // N  (total ~3.2 MB)

    hipMemsetAsync(deg, 0, NN * sizeof(float), stream);

    mlp12_kernel<<<8, 64, 0, stream>>>(x, W1, b1, W2, b2, h2);
    deg_kernel<<<(NE + 255) / 256, 256, 0, stream>>>(dst, deg);
    big_layer_kernel<<<(NN + 63) / 64, 256, 0, stream>>>(h2, W3, b3, Wg1, m1);
    node1_kernel<<<(NN + 255) / 256, 256, 0, stream>>>(deg, m1, dinv, agg1);
    edge1_kernel<<<(NE + 255) / 256, 256, 0, stream>>>(src, dst, dinv, m1, agg1);
    node2_kernel<<<(NN + 255) / 256, 256, 0, stream>>>(agg1, bg1, Wg2, deg, m2, agg2);
    edge2_kernel<<<(NE + 255) / 256, 256, 0, stream>>>(src, dst, dinv, m2, agg2);
    sigmoid_kernel<<<(NN + 255) / 256, 256, 0, stream>>>(agg2, bg2, out);
}

// Round 2
// 1733.018 us; speedup vs baseline: 1.0076x; 1.0076x over previous
//
#include <hip/hip_runtime.h>
#include <math.h>

#define NN 100000
#define NE 3200000
#define BL_BLOCKS 782   // ceil(NN / 128)

// ---------------- K1: h1 = relu(x@W1+b1); h2 = relu(h1@W2+b2) ----------------
__global__ __launch_bounds__(64) void mlp12_kernel(
        const float* __restrict__ x,
        const float* __restrict__ W1, const float* __restrict__ b1,
        const float* __restrict__ W2, const float* __restrict__ b2,
        float* __restrict__ h2g) {
    __shared__ float xs[128];
    __shared__ float h1s[256];
    int t = threadIdx.x;
    xs[t] = x[t];
    xs[t + 64] = x[t + 64];
    __syncthreads();
    for (int cc = 0; cc < 4; ++cc) {
        int c = t + cc * 64;
        float acc = b1[c];
        for (int k = 0; k < 128; ++k) acc = fmaf(xs[k], W1[k * 256 + c], acc);
        h1s[c] = fmaxf(acc, 0.0f);
    }
    __syncthreads();
    int c2 = blockIdx.x * 64 + t;
    float acc = b2[c2];
    for (int k = 0; k < 256; ++k) acc = fmaf(h1s[k], W2[k * 512 + c2], acc);
    h2g[c2] = fmaxf(acc, 0.0f);
}

// ------- K2: h3 = relu(h2@W3+b3); m1 = h3@Wg1; FUSED deg scatter -------------
// 256 thr = 4 k-slices (1 wave each) x 64 lanes; each lane owns 2 consecutive
// nodes -> 2KB contiguous per wave-iteration (vs 1KB before), 8 accumulators.
__global__ __launch_bounds__(256) void big_layer_kernel(
        const float* __restrict__ h2, const float* __restrict__ W3,
        const float* __restrict__ b3, const float* __restrict__ Wg1,
        const int* __restrict__ dst, float* __restrict__ deg,
        float* __restrict__ m1) {
    __shared__ float h2s[512];
    __shared__ float ps[4][128][4];   // 8 KB partials
    int t = threadIdx.x;
    h2s[t] = h2[t];
    h2s[t + 256] = h2[t + 256];
    __syncthreads();
    int ks = t >> 6;          // k-slice 0..3 (one wave each)
    int lane = t & 63;
    int nb = blockIdx.x * 128;
    int n0 = nb + 2 * lane;   // 2 consecutive nodes per lane
    float a0=0.f,a1=0.f,a2=0.f,a3=0.f,a4=0.f,a5=0.f,a6=0.f,a7=0.f;
    if (n0 < NN) {            // n0 even, NN even => n0+1 < NN too
        const float* q = W3 + (size_t)(ks * 128) * 400000 + 4 * (size_t)n0;
        #pragma unroll 8
        for (int it = 0; it < 128; ++it) {
            float4 w0 = *reinterpret_cast<const float4*>(q);
            float4 w1 = *reinterpret_cast<const float4*>(q + 4);
            float hv = h2s[ks * 128 + it];
            a0 = fmaf(hv, w0.x, a0); a1 = fmaf(hv, w0.y, a1);
            a2 = fmaf(hv, w0.z, a2); a3 = fmaf(hv, w0.w, a3);
            a4 = fmaf(hv, w1.x, a4); a5 = fmaf(hv, w1.y, a5);
            a6 = fmaf(hv, w1.z, a6); a7 = fmaf(hv, w1.w, a7);
            q += 400000;
        }
    }
    *reinterpret_cast<float4*>(&ps[ks][2 * lane][0])     = make_float4(a0, a1, a2, a3);
    *reinterpret_cast<float4*>(&ps[ks][2 * lane + 1][0]) = make_float4(a4, a5, a6, a7);
    // fused degree scatter (fire-and-forget atomics overlap the HBM stream)
    for (int e = blockIdx.x * 256 + t; e < NE; e += BL_BLOCKS * 256)
        atomicAdd(&deg[dst[e]], 1.0f);
    __syncthreads();
    if (t < 128) {
        int node = nb + t;
        if (node < NN) {
            float4 s0 = *reinterpret_cast<float4*>(&ps[0][t][0]);
            float4 s1 = *reinterpret_cast<float4*>(&ps[1][t][0]);
            float4 s2 = *reinterpret_cast<float4*>(&ps[2][t][0]);
            float4 s3 = *reinterpret_cast<float4*>(&ps[3][t][0]);
            float4 bb = *reinterpret_cast<const float4*>(b3 + 4 * (size_t)node);
            float t0 = fmaxf(s0.x + s1.x + s2.x + s3.x + bb.x, 0.0f);
            float t1 = fmaxf(s0.y + s1.y + s2.y + s3.y + bb.y, 0.0f);
            float t2 = fmaxf(s0.z + s1.z + s2.z + s3.z + bb.z, 0.0f);
            float t3 = fmaxf(s0.w + s1.w + s2.w + s3.w + bb.w, 0.0f);
            float m0 = t0 * Wg1[0] + t1 * Wg1[2] + t2 * Wg1[4] + t3 * Wg1[6];
            float mv = t0 * Wg1[1] + t1 * Wg1[3] + t2 * Wg1[5] + t3 * Wg1[7];
            reinterpret_cast<float2*>(m1)[node] = make_float2(m0, mv);
        }
    }
}

// ---------------- K3: dinv = rsqrt(deg+1); agg1 = m1 * (1/deg) ---------------
__global__ __launch_bounds__(256) void node1_kernel(const float* __restrict__ deg,
                                                    const float* __restrict__ m1,
                                                    float* __restrict__ dinv,
                                                    float* __restrict__ agg1) {
    int i = blockIdx.x * 256 + threadIdx.x;
    if (i < NN) {
        float d = deg[i] + 1.0f;
        dinv[i] = rsqrtf(d);
        float inv = 1.0f / d;
        float2 mv = reinterpret_cast<const float2*>(m1)[i];
        reinterpret_cast<float2*>(agg1)[i] = make_float2(mv.x * inv, mv.y * inv);
    }
}

// ---------------- K4: GCN1 edge scatter, 4 edges/thread, cache norm ----------
__global__ __launch_bounds__(256) void edge1_kernel(const int* __restrict__ src,
                                                    const int* __restrict__ dst,
                                                    const float* __restrict__ dinv,
                                                    const float* __restrict__ m1,
                                                    float* __restrict__ norm,
                                                    float* __restrict__ agg1) {
    int i = blockIdx.x * 256 + threadIdx.x;   // group of 4 edges (NE % 4 == 0)
    if (i * 4 >= NE) return;
    int4 s4 = reinterpret_cast<const int4*>(src)[i];
    int4 d4 = reinterpret_cast<const int4*>(dst)[i];
    const float2* m1f2 = reinterpret_cast<const float2*>(m1);
    float n0 = dinv[s4.x] * dinv[d4.x];
    float n1 = dinv[s4.y] * dinv[d4.y];
    float n2 = dinv[s4.z] * dinv[d4.z];
    float n3 = dinv[s4.w] * dinv[d4.w];
    float2 v0 = m1f2[s4.x];
    float2 v1 = m1f2[s4.y];
    float2 v2 = m1f2[s4.z];
    float2 v3 = m1f2[s4.w];
    reinterpret_cast<float4*>(norm)[i] = make_float4(n0, n1, n2, n3);
    atomicAdd(&agg1[2 * d4.x],     v0.x * n0);
    atomicAdd(&agg1[2 * d4.x + 1], v0.y * n0);
    atomicAdd(&agg1[2 * d4.y],     v1.x * n1);
    atomicAdd(&agg1[2 * d4.y + 1], v1.y * n1);
    atomicAdd(&agg1[2 * d4.z],     v2.x * n2);
    atomicAdd(&agg1[2 * d4.z + 1], v2.y * n2);
    atomicAdd(&agg1[2 * d4.w],     v3.x * n3);
    atomicAdd(&agg1[2 * d4.w + 1], v3.y * n3);
}

// ------- K5: g1 = relu(agg1+bg1); m2 = g1@Wg2; agg2 = m2*(1/deg) -------------
__global__ __launch_bounds__(256) void node2_kernel(const float* __restrict__ agg1,
                                                    const float* __restrict__ bg1,
                                                    const float* __restrict__ Wg2,
                                                    const float* __restrict__ deg,
                                                    float* __restrict__ m2,
                                                    float* __restrict__ agg2) {
    int i = blockIdx.x * 256 + threadIdx.x;
    if (i < NN) {
        float2 av = reinterpret_cast<const float2*>(agg1)[i];
        float g0 = fmaxf(av.x + bg1[0], 0.0f);
        float g1 = fmaxf(av.y + bg1[1], 0.0f);
        float mv = g0 * Wg2[0] + g1 * Wg2[1];
        m2[i] = mv;
        agg2[i] = mv / (deg[i] + 1.0f);
    }
}

// ---------------- K6: GCN2 edge scatter, reuse norm, 4 edges/thread ----------
__global__ __launch_bounds__(256) void edge2_kernel(const int* __restrict__ src,
                                                    const int* __restrict__ dst,
                                                    const float* __restrict__ norm,
                                                    const float* __restrict__ m2,
                                                    float* __restrict__ agg2) {
    int i = blockIdx.x * 256 + threadIdx.x;
    if (i * 4 >= NE) return;
    int4 s4 = reinterpret_cast<const int4*>(src)[i];
    int4 d4 = reinterpret_cast<const int4*>(dst)[i];
    float4 nv = reinterpret_cast<const float4*>(norm)[i];
    atomicAdd(&agg2[d4.x], m2[s4.x] * nv.x);
    atomicAdd(&agg2[d4.y], m2[s4.y] * nv.y);
    atomicAdd(&agg2[d4.z], m2[s4.z] * nv.z);
    atomicAdd(&agg2[d4.w], m2[s4.w] * nv.w);
}

// ---------------- K7: out = sigmoid(agg2 + bg2) ------------------------------
__global__ __launch_bounds__(256) void sigmoid_kernel(const float* __restrict__ agg2,
                                                      const float* __restrict__ bg2,
                                                      float* __restrict__ out) {
    int i = blockIdx.x * 256 + threadIdx.x;
    if (i < NN) {
        float v = agg2[i] + bg2[0];
        out[i] = 1.0f / (1.0f + __expf(-v));
    }
}

extern "C" void kernel_launch(void* const* d_in, const int* in_sizes, int n_in,
                              void* d_out, int out_size, void* d_ws, size_t ws_size,
                              hipStream_t stream) {
    const float* x   = (const float*)d_in[0];
    const int*   ei  = (const int*)d_in[1];     // (2, E)
    const float* W1  = (const float*)d_in[2];
    const float* b1  = (const float*)d_in[3];
    const float* W2  = (const float*)d_in[4];
    const float* b2  = (const float*)d_in[5];
    const float* W3  = (const float*)d_in[6];
    const float* b3  = (const float*)d_in[7];
    const float* Wg1 = (const float*)d_in[8];
    const float* bg1 = (const float*)d_in[9];
    const float* Wg2 = (const float*)d_in[10];
    const float* bg2 = (const float*)d_in[11];
    float* out = (float*)d_out;

    const int* src = ei;
    const int* dst = ei + NE;

    // workspace layout (floats)
    float* ws   = (float*)d_ws;
    float* h2   = ws;                   // 512
    float* m1   = h2 + 512;             // 2N
    float* deg  = m1 + 2 * NN;          // N
    float* dinv = deg + NN;             // N
    float* agg1 = dinv + NN;            // 2N
    float* m2   = agg1 + 2 * NN;        // N
    float* agg2 = m2 + NN;              // N
    float* norm = agg2 + NN;            // E (12.8 MB), 16B-aligned offset

    hipMemsetAsync(deg, 0, NN * sizeof(float), stream);

    mlp12_kernel<<<8, 64, 0, stream>>>(x, W1, b1, W2, b2, h2);
    big_layer_kernel<<<BL_BLOCKS, 256, 0, stream>>>(h2, W3, b3, Wg1, dst, deg, m1);
    node1_kernel<<<(NN + 255) / 256, 256, 0, stream>>>(deg, m1, dinv, agg1);
    edge1_kernel<<<(NE / 4 + 255) / 256, 256, 0, stream>>>(src, dst, dinv, m1, norm, agg1);
    node2_kernel<<<(NN + 255) / 256, 256, 0, stream>>>(agg1, bg1, Wg2, deg, m2, agg2);
    edge2_kernel<<<(NE / 4 + 255) / 256, 256, 0, stream>>>(src, dst, norm, m2, agg2);
    sigmoid_kernel<<<(NN + 255) / 256, 256, 0, stream>>>(agg2, bg2, out);
}